// Round 6
// baseline (155.211 us; speedup 1.0000x reference)
//
#include <hip/hip_runtime.h>
#include <hip/hip_bf16.h>

#define BATCH 8
#define CIN   64
#define COUT  64
#define HH    128
#define WW    128
#define HW    (HH * WW)
#define OFFC  18
#define KK    9

typedef __attribute__((ext_vector_type(8))) short short8;
typedef __attribute__((ext_vector_type(8))) unsigned short ushort8;
typedef __attribute__((ext_vector_type(4))) float f32x4;

__device__ __forceinline__ float bf2f(unsigned short u) {
    return __builtin_bit_cast(float, ((unsigned int)u) << 16);
}
__device__ __forceinline__ short f2bf(float v) {
    __hip_bfloat16 h = __float2bfloat16(v);
    return __builtin_bit_cast(short, h);
}

// ------- Kernel X: x (b,c,h,w) f32 -> xT (b,h,w,c) bf16, one (b,ho) row per block -------
__global__ __launch_bounds__(256) void to_chlast_k(
    const float* __restrict__ x, unsigned short* __restrict__ xT)
{
    __shared__ unsigned short t[128 * 72];   // [w][c], pad 72 keeps 16B-aligned ushort8 rows
    int blk = blockIdx.x;                    // b*HH + ho
    int ho = blk & (HH - 1);
    int b  = blk >> 7;
    int tid = threadIdx.x;

    const float* xr = x + (size_t)b * CIN * HW + ho * WW;
    for (int i = tid; i < 2048; i += 256) {  // c = i>>5, 4 consecutive w
        int c = i >> 5, w4 = (i & 31) * 4;
        float4 v = *(const float4*)(xr + (size_t)c * HW + w4);
        t[(w4 + 0) * 72 + c] = (unsigned short)f2bf(v.x);
        t[(w4 + 1) * 72 + c] = (unsigned short)f2bf(v.y);
        t[(w4 + 2) * 72 + c] = (unsigned short)f2bf(v.z);
        t[(w4 + 3) * 72 + c] = (unsigned short)f2bf(v.w);
    }
    __syncthreads();

    unsigned short* orow = xT + (size_t)blk * WW * 64;
    for (int j = tid; j < 1024; j += 256) {  // w = j>>3, 8 channels
        int w = j >> 3, c8 = (j & 7) * 8;
        *(ushort8*)(orow + w * 64 + c8) = *(const ushort8*)(t + w * 72 + c8);
    }
}

// ------- Kernel B: w_deform (o,c,kh,kw) -> bf16 B-fragments wf[kk][nt(4)][lane][8] -------
// B[k=kk*32+(lane>>4)*8+j][col=lane&15] = w[o=nt*16+col][ck=k], ck = tap*64+c
__global__ __launch_bounds__(256) void build_wfrag_k(
    const float* __restrict__ wd, unsigned short* __restrict__ wf)
{
    int idx = blockIdx.x * 256 + threadIdx.x;   // o*576 + ck, 36864 total
    int ck = idx % 576;
    int o  = idx / 576;
    int c = ck & 63, k = ck >> 6;
    float v = wd[o * 576 + c * 9 + k];
    int kk = ck >> 5, nt = o >> 4;
    int lane = (o & 15) | (((ck >> 3) & 3) << 4);
    int j = ck & 7;
    wf[((kk * 4 + nt) * 64 + lane) * 8 + j] = (unsigned short)f2bf(v);
}

// ------- Kernel B2: w_offset (18,64,3,3) -> bf16 B-fragments wfo[kk][nt(2)][lane][8] -------
// N padded 18->32 with zero columns; K = tap*64 + c.
__global__ __launch_bounds__(256) void build_wfo_k(
    const float* __restrict__ wo, unsigned short* __restrict__ wfo)
{
    int idx = blockIdx.x * 256 + threadIdx.x;   // ov*576 + ck, ov = 0..31 (virtual oc)
    if (idx >= 32 * 576) return;
    int ck = idx % 576;
    int ov = idx / 576;
    int c = ck & 63, tap = ck >> 6;
    float v = (ov < OFFC) ? wo[ov * 576 + c * 9 + tap] : 0.f;
    int kk = ck >> 5, nt = ov >> 4;
    int lane = (ov & 15) | (((ck >> 3) & 3) << 4);
    int j = ck & 7;
    wfo[((kk * 2 + nt) * 64 + lane) * 8 + j] = (unsigned short)f2bf(v);
}

// ---------------- Kernel C: fused offsets-conv + gather + deform MFMA ----------------
// Block = 64 pixels (half-row) x 64 outputs, 4 waves x 16 pixels.
// LDS = 18,944 B -> 8 blocks/CU resident (one full round, no ragged tail);
// __launch_bounds__(256,8) pins <=64 VGPR so 32 waves/CU are legal.
// posI compressed to int2: corner00 index + packed ((dyW<<1)|dx); other corners
// reconstructed with 3 adds (border clamp: dx/dyW are 0 there, weights masked).
__global__ __launch_bounds__(256, 8) void deform_fused_k(
    const unsigned short* __restrict__ xT,
    const short8* __restrict__ wfo,
    const short8* __restrict__ wf, float* __restrict__ out)
{
    __shared__ alignas(16) char smem[18944];
    float*  offsL = (float*)smem;                     // [64][20] = 5120 B
    int2*   posI  = (int2*)(smem + 5120);             // 576*8  = 4608 B
    float4* posW  = (float4*)(smem + 5120 + 4608);    // 576*16 = 9216 B
    float*  trans = (float*)smem;                     // 64*65*4 = 16640 B, aliases all (post-loop)

    int tid  = threadIdx.x;
    int blk  = blockIdx.x;               // (ho*2+wseg)*8 + b
    int b    = blk & 7;
    int t    = blk >> 3;
    int wseg = t & 1;
    int ho   = t >> 1;
    int wo0  = wseg * 64;

    const unsigned short* pT = xT + (size_t)b * HW * 64;

    int lane  = tid & 63;
    int wave  = tid >> 6;
    int prow  = lane & 15;               // pixel within wave tile
    int khalf = lane >> 4;               // k-subchunk

    // ---- phase A: offsets = conv3x3(x, w_offset) via MFMA, results to offsL ----
    {
        int wo = wo0 + wave * 16 + prow;
        f32x4 oa0 = {0.f, 0.f, 0.f, 0.f};
        f32x4 oa1 = {0.f, 0.f, 0.f, 0.f};
        #pragma unroll
        for (int kk = 0; kk < 18; ++kk) {
            int tap = kk >> 1;
            int y  = ho + tap / 3 - 1;
            int xw = wo + tap % 3 - 1;
            int c0 = ((kk & 1) << 5) + (khalf << 3);
            short8 a = {0, 0, 0, 0, 0, 0, 0, 0};
            if ((unsigned)y < HH && (unsigned)xw < WW)
                a = *(const short8*)(pT + (((size_t)(y * WW + xw)) << 6) + c0);
            short8 b0 = wfo[(kk * 2 + 0) * 64 + lane];
            short8 b1 = wfo[(kk * 2 + 1) * 64 + lane];
            oa0 = __builtin_amdgcn_mfma_f32_16x16x32_bf16(a, b0, oa0, 0, 0, 0);
            oa1 = __builtin_amdgcn_mfma_f32_16x16x32_bf16(a, b1, oa1, 0, 0, 0);
        }
        int ocol = lane & 15;
        int pix0 = wave * 16 + khalf * 4;
        #pragma unroll
        for (int r = 0; r < 4; ++r)
            offsL[(pix0 + r) * 20 + ocol] = oa0[r];
        if (ocol < 2) {
            #pragma unroll
            for (int r = 0; r < 4; ++r)
                offsL[(pix0 + r) * 20 + 16 + ocol] = oa1[r];
        }
    }
    __syncthreads();

    // ---- phase 0: 64 pixels x 9 taps -> compressed corner indices + pre-masked weights ----
    for (int e = tid; e < 576; e += 256) {
        int p = e / 9, k = e - p * 9;
        int wo = wo0 + p;
        float dy = offsL[p * 20 + 2 * k];
        float dx = offsL[p * 20 + 2 * k + 1];
        float yy = (float)(ho - 1 + k / 3) + dy;
        float xx = (float)(wo - 1 + k % 3) + dx;
        float y0 = floorf(yy), x0 = floorf(xx);
        float wy1 = yy - y0, wx1 = xx - x0;
        float wy0 = 1.f - wy1, wx0 = 1.f - wx1;
        bool valid = (yy > -1.f) && (yy < (float)HH) && (xx > -1.f) && (xx < (float)WW);
        int y0i = (int)y0, x0i = (int)x0;
        bool iy0 = (unsigned)y0i < HH, iy1 = (unsigned)(y0i + 1) < HH;
        bool ix0 = (unsigned)x0i < WW, ix1 = (unsigned)(x0i + 1) < WW;
        float m00 = (valid && iy0 && ix0) ? 1.f : 0.f;
        float m01 = (valid && iy0 && ix1) ? 1.f : 0.f;
        float m10 = (valid && iy1 && ix0) ? 1.f : 0.f;
        float m11 = (valid && iy1 && ix1) ? 1.f : 0.f;
        int yc0 = min(max(y0i, 0), HH - 1), yc1 = min(max(y0i + 1, 0), HH - 1);
        int xc0 = min(max(x0i, 0), WW - 1), xc1 = min(max(x0i + 1, 0), WW - 1);
        int idx00 = yc0 * WW + xc0;
        int ddx   = xc1 - xc0;                   // 0 or 1
        int dyw   = (yc1 - yc0) * WW;            // 0 or WW
        posI[e] = make_int2(idx00, (dyw << 1) | ddx);
        posW[e] = make_float4(wy0 * wx0 * m00, wy0 * wx1 * m01, wy1 * wx0 * m10, wy1 * wx1 * m11);
    }
    __syncthreads();

    // ---- phase 1: gather + MFMA ----
    int ebase = (wave * 16 + prow) * 9;

    f32x4 acc0 = {0.f, 0.f, 0.f, 0.f};
    f32x4 acc1 = {0.f, 0.f, 0.f, 0.f};
    f32x4 acc2 = {0.f, 0.f, 0.f, 0.f};
    f32x4 acc3 = {0.f, 0.f, 0.f, 0.f};

    #pragma unroll 2
    for (int kk = 0; kk < 18; ++kk) {
        int tap = kk >> 1;
        short8 bf0 = wf[(kk * 4 + 0) * 64 + lane];
        short8 bf1 = wf[(kk * 4 + 1) * 64 + lane];
        short8 bf2 = wf[(kk * 4 + 2) * 64 + lane];
        short8 bf3 = wf[(kk * 4 + 3) * 64 + lane];
        int2   io2 = posI[ebase + tap];
        float4 w4  = posW[ebase + tap];
        int i00 = io2.x;
        int ddx = io2.y & 1;
        int dyw = io2.y >> 1;
        int i01 = i00 + ddx;
        int i10 = i00 + dyw;
        int i11 = i10 + ddx;
        int c0 = ((kk & 1) << 5) + (khalf << 3);
        const unsigned short* bp = pT + c0;
        ushort8 s0 = *(const ushort8*)(bp + (size_t)i00 * 64);
        ushort8 s1 = *(const ushort8*)(bp + (size_t)i01 * 64);
        ushort8 s2 = *(const ushort8*)(bp + (size_t)i10 * 64);
        ushort8 s3 = *(const ushort8*)(bp + (size_t)i11 * 64);
        short8 a;
        #pragma unroll
        for (int j = 0; j < 8; ++j) {
            float v = w4.x * bf2f(s0[j]) + w4.y * bf2f(s1[j])
                    + w4.z * bf2f(s2[j]) + w4.w * bf2f(s3[j]);
            a[j] = f2bf(v);
        }
        acc0 = __builtin_amdgcn_mfma_f32_16x16x32_bf16(a, bf0, acc0, 0, 0, 0);
        acc1 = __builtin_amdgcn_mfma_f32_16x16x32_bf16(a, bf1, acc1, 0, 0, 0);
        acc2 = __builtin_amdgcn_mfma_f32_16x16x32_bf16(a, bf2, acc2, 0, 0, 0);
        acc3 = __builtin_amdgcn_mfma_f32_16x16x32_bf16(a, bf3, acc3, 0, 0, 0);
    }
    __syncthreads();                     // pos arrays dead; reuse as trans

    // D layout: col=lane&15 (o within tile), row=(lane>>4)*4+reg (pixel within wave)
    int ocol = lane & 15;
    int pr   = wave * 16 + khalf * 4;
    #pragma unroll
    for (int r = 0; r < 4; ++r) {
        trans[(0 * 16 + ocol) * 65 + pr + r] = acc0[r];
        trans[(1 * 16 + ocol) * 65 + pr + r] = acc1[r];
        trans[(2 * 16 + ocol) * 65 + pr + r] = acc2[r];
        trans[(3 * 16 + ocol) * 65 + pr + r] = acc3[r];
    }
    __syncthreads();

    float* ob = out + ((size_t)b * COUT * HH + ho) * WW + wo0;
    for (int i = tid; i < 64 * 64; i += 256) {
        int o = i >> 6, w = i & 63;
        ob[(size_t)o * HW + w] = trans[o * 65 + w];
    }
}

extern "C" void kernel_launch(void* const* d_in, const int* in_sizes, int n_in,
                              void* d_out, int out_size, void* d_ws, size_t ws_size,
                              hipStream_t stream)
{
    const float* x    = (const float*)d_in[0];
    const float* woff = (const float*)d_in[1];
    const float* wdef = (const float*)d_in[2];
    float* out  = (float*)d_out;

    unsigned short* wfrag = (unsigned short*)d_ws;          // 36864 ush = 73.7 KB
    unsigned short* wfo   = wfrag + 36864;                  // 18432 ush = 36.9 KB
    unsigned short* xT    = wfo + 18432;                    // 8*16384*64 ush = 16.8 MB

    hipLaunchKernelGGL(to_chlast_k, dim3(BATCH * HH), dim3(256), 0, stream,
                       x, xT);
    hipLaunchKernelGGL(build_wfrag_k, dim3(COUT * 576 / 256), dim3(256), 0, stream,
                       wdef, wfrag);
    hipLaunchKernelGGL(build_wfo_k, dim3(32 * 576 / 256), dim3(256), 0, stream,
                       woff, wfo);
    hipLaunchKernelGGL(deform_fused_k, dim3(BATCH * HH * 2), dim3(256), 0, stream,
                       xT, (const short8*)wfo, (const short8*)wfrag, out);
}

// Round 7
// 122.922 us; speedup vs baseline: 1.2627x; 1.2627x over previous
//
#include <hip/hip_runtime.h>
#include <hip/hip_bf16.h>

#define BATCH 8
#define CIN   64
#define COUT  64
#define HH    128
#define WW    128
#define HW    (HH * WW)
#define OFFC  18
#define KK    9

typedef __attribute__((ext_vector_type(8))) short short8;
typedef __attribute__((ext_vector_type(8))) unsigned short ushort8;
typedef __attribute__((ext_vector_type(4))) float f32x4;

__device__ __forceinline__ float bf2f(unsigned short u) {
    return __builtin_bit_cast(float, ((unsigned int)u) << 16);
}
__device__ __forceinline__ short f2bf(float v) {
    __hip_bfloat16 h = __float2bfloat16(v);
    return __builtin_bit_cast(short, h);
}

// ------- Kernel X: x (b,c,h,w) f32 -> xT (b,h,w,c) bf16, one (b,ho) row per block -------
__global__ __launch_bounds__(256) void to_chlast_k(
    const float* __restrict__ x, unsigned short* __restrict__ xT)
{
    __shared__ unsigned short t[128 * 72];   // [w][c], pad 72 keeps 16B-aligned ushort8 rows
    int blk = blockIdx.x;                    // b*HH + ho
    int ho = blk & (HH - 1);
    int b  = blk >> 7;
    int tid = threadIdx.x;

    const float* xr = x + (size_t)b * CIN * HW + ho * WW;
    for (int i = tid; i < 2048; i += 256) {  // c = i>>5, 4 consecutive w
        int c = i >> 5, w4 = (i & 31) * 4;
        float4 v = *(const float4*)(xr + (size_t)c * HW + w4);
        t[(w4 + 0) * 72 + c] = (unsigned short)f2bf(v.x);
        t[(w4 + 1) * 72 + c] = (unsigned short)f2bf(v.y);
        t[(w4 + 2) * 72 + c] = (unsigned short)f2bf(v.z);
        t[(w4 + 3) * 72 + c] = (unsigned short)f2bf(v.w);
    }
    __syncthreads();

    unsigned short* orow = xT + (size_t)blk * WW * 64;
    for (int j = tid; j < 1024; j += 256) {  // w = j>>3, 8 channels
        int w = j >> 3, c8 = (j & 7) * 8;
        *(ushort8*)(orow + w * 64 + c8) = *(const ushort8*)(t + w * 72 + c8);
    }
}

// ------- Kernel B: w_deform (o,c,kh,kw) -> bf16 B-fragments wf[kk][nt(4)][lane][8] -------
// B[k=kk*32+(lane>>4)*8+j][col=lane&15] = w[o=nt*16+col][ck=k], ck = tap*64+c
__global__ __launch_bounds__(256) void build_wfrag_k(
    const float* __restrict__ wd, unsigned short* __restrict__ wf)
{
    int idx = blockIdx.x * 256 + threadIdx.x;   // o*576 + ck, 36864 total
    int ck = idx % 576;
    int o  = idx / 576;
    int c = ck & 63, k = ck >> 6;
    float v = wd[o * 576 + c * 9 + k];
    int kk = ck >> 5, nt = o >> 4;
    int lane = (o & 15) | (((ck >> 3) & 3) << 4);
    int j = ck & 7;
    wf[((kk * 4 + nt) * 64 + lane) * 8 + j] = (unsigned short)f2bf(v);
}

// ------- Kernel B2: w_offset (18,64,3,3) -> bf16 B-fragments wfo[kk][nt(2)][lane][8] -------
// N padded 18->32 with zero columns; K = tap*64 + c.
__global__ __launch_bounds__(256) void build_wfo_k(
    const float* __restrict__ wo, unsigned short* __restrict__ wfo)
{
    int idx = blockIdx.x * 256 + threadIdx.x;   // ov*576 + ck, ov = 0..31 (virtual oc)
    if (idx >= 32 * 576) return;
    int ck = idx % 576;
    int ov = idx / 576;
    int c = ck & 63, tap = ck >> 6;
    float v = (ov < OFFC) ? wo[ov * 576 + c * 9 + tap] : 0.f;
    int kk = ck >> 5, nt = ov >> 4;
    int lane = (ov & 15) | (((ck >> 3) & 3) << 4);
    int j = ck & 7;
    wfo[((kk * 2 + nt) * 64 + lane) * 8 + j] = (unsigned short)f2bf(v);
}

// ---------------- Kernel C: fused offsets-conv + gather + deform MFMA ----------------
// Block = 64 pixels (half-row) x 64 outputs, 4 waves x 16 pixels.
// LDS = 18,944 B -> 8 blocks/CU fit by LDS. NO min-wave bound: R6 showed forcing
// 8 waves/EU caps VGPR at 32 and serializes the gather (151 us vs 111). Compiler
// picks ~52 VGPR (<=64 boundary) -> HW can still co-schedule 8 blocks/CU.
// posI compressed to int2: corner00 index + packed ((dyW<<1)|dx); other corners
// reconstructed with 3 adds (border clamp: dx/dyW are 0 there, weights masked).
__global__ __launch_bounds__(256) void deform_fused_k(
    const unsigned short* __restrict__ xT,
    const short8* __restrict__ wfo,
    const short8* __restrict__ wf, float* __restrict__ out)
{
    __shared__ alignas(16) char smem[18944];
    float*  offsL = (float*)smem;                     // [64][20] = 5120 B
    int2*   posI  = (int2*)(smem + 5120);             // 576*8  = 4608 B
    float4* posW  = (float4*)(smem + 5120 + 4608);    // 576*16 = 9216 B
    float*  trans = (float*)smem;                     // 64*65*4 = 16640 B, aliases all (post-loop)

    int tid  = threadIdx.x;
    int blk  = blockIdx.x;               // (ho*2+wseg)*8 + b
    int b    = blk & 7;
    int t    = blk >> 3;
    int wseg = t & 1;
    int ho   = t >> 1;
    int wo0  = wseg * 64;

    const unsigned short* pT = xT + (size_t)b * HW * 64;

    int lane  = tid & 63;
    int wave  = tid >> 6;
    int prow  = lane & 15;               // pixel within wave tile
    int khalf = lane >> 4;               // k-subchunk

    // ---- phase A: offsets = conv3x3(x, w_offset) via MFMA, results to offsL ----
    {
        int wo = wo0 + wave * 16 + prow;
        f32x4 oa0 = {0.f, 0.f, 0.f, 0.f};
        f32x4 oa1 = {0.f, 0.f, 0.f, 0.f};
        #pragma unroll
        for (int kk = 0; kk < 18; ++kk) {
            int tap = kk >> 1;
            int y  = ho + tap / 3 - 1;
            int xw = wo + tap % 3 - 1;
            int c0 = ((kk & 1) << 5) + (khalf << 3);
            short8 a = {0, 0, 0, 0, 0, 0, 0, 0};
            if ((unsigned)y < HH && (unsigned)xw < WW)
                a = *(const short8*)(pT + (((size_t)(y * WW + xw)) << 6) + c0);
            short8 b0 = wfo[(kk * 2 + 0) * 64 + lane];
            short8 b1 = wfo[(kk * 2 + 1) * 64 + lane];
            oa0 = __builtin_amdgcn_mfma_f32_16x16x32_bf16(a, b0, oa0, 0, 0, 0);
            oa1 = __builtin_amdgcn_mfma_f32_16x16x32_bf16(a, b1, oa1, 0, 0, 0);
        }
        int ocol = lane & 15;
        int pix0 = wave * 16 + khalf * 4;
        #pragma unroll
        for (int r = 0; r < 4; ++r)
            offsL[(pix0 + r) * 20 + ocol] = oa0[r];
        if (ocol < 2) {
            #pragma unroll
            for (int r = 0; r < 4; ++r)
                offsL[(pix0 + r) * 20 + 16 + ocol] = oa1[r];
        }
    }
    __syncthreads();

    // ---- phase 0: 64 pixels x 9 taps -> compressed corner indices + pre-masked weights ----
    for (int e = tid; e < 576; e += 256) {
        int p = e / 9, k = e - p * 9;
        int wo = wo0 + p;
        float dy = offsL[p * 20 + 2 * k];
        float dx = offsL[p * 20 + 2 * k + 1];
        float yy = (float)(ho - 1 + k / 3) + dy;
        float xx = (float)(wo - 1 + k % 3) + dx;
        float y0 = floorf(yy), x0 = floorf(xx);
        float wy1 = yy - y0, wx1 = xx - x0;
        float wy0 = 1.f - wy1, wx0 = 1.f - wx1;
        bool valid = (yy > -1.f) && (yy < (float)HH) && (xx > -1.f) && (xx < (float)WW);
        int y0i = (int)y0, x0i = (int)x0;
        bool iy0 = (unsigned)y0i < HH, iy1 = (unsigned)(y0i + 1) < HH;
        bool ix0 = (unsigned)x0i < WW, ix1 = (unsigned)(x0i + 1) < WW;
        float m00 = (valid && iy0 && ix0) ? 1.f : 0.f;
        float m01 = (valid && iy0 && ix1) ? 1.f : 0.f;
        float m10 = (valid && iy1 && ix0) ? 1.f : 0.f;
        float m11 = (valid && iy1 && ix1) ? 1.f : 0.f;
        int yc0 = min(max(y0i, 0), HH - 1), yc1 = min(max(y0i + 1, 0), HH - 1);
        int xc0 = min(max(x0i, 0), WW - 1), xc1 = min(max(x0i + 1, 0), WW - 1);
        int idx00 = yc0 * WW + xc0;
        int ddx   = xc1 - xc0;                   // 0 or 1
        int dyw   = (yc1 - yc0) * WW;            // 0 or WW
        posI[e] = make_int2(idx00, (dyw << 1) | ddx);
        posW[e] = make_float4(wy0 * wx0 * m00, wy0 * wx1 * m01, wy1 * wx0 * m10, wy1 * wx1 * m11);
    }
    __syncthreads();

    // ---- phase 1: gather + MFMA ----
    int ebase = (wave * 16 + prow) * 9;

    f32x4 acc0 = {0.f, 0.f, 0.f, 0.f};
    f32x4 acc1 = {0.f, 0.f, 0.f, 0.f};
    f32x4 acc2 = {0.f, 0.f, 0.f, 0.f};
    f32x4 acc3 = {0.f, 0.f, 0.f, 0.f};

    #pragma unroll 2
    for (int kk = 0; kk < 18; ++kk) {
        int tap = kk >> 1;
        short8 bf0 = wf[(kk * 4 + 0) * 64 + lane];
        short8 bf1 = wf[(kk * 4 + 1) * 64 + lane];
        short8 bf2 = wf[(kk * 4 + 2) * 64 + lane];
        short8 bf3 = wf[(kk * 4 + 3) * 64 + lane];
        int2   io2 = posI[ebase + tap];
        float4 w4  = posW[ebase + tap];
        int i00 = io2.x;
        int ddx = io2.y & 1;
        int dyw = io2.y >> 1;
        int i01 = i00 + ddx;
        int i10 = i00 + dyw;
        int i11 = i10 + ddx;
        int c0 = ((kk & 1) << 5) + (khalf << 3);
        const unsigned short* bp = pT + c0;
        ushort8 s0 = *(const ushort8*)(bp + (size_t)i00 * 64);
        ushort8 s1 = *(const ushort8*)(bp + (size_t)i01 * 64);
        ushort8 s2 = *(const ushort8*)(bp + (size_t)i10 * 64);
        ushort8 s3 = *(const ushort8*)(bp + (size_t)i11 * 64);
        short8 a;
        #pragma unroll
        for (int j = 0; j < 8; ++j) {
            float v = w4.x * bf2f(s0[j]) + w4.y * bf2f(s1[j])
                    + w4.z * bf2f(s2[j]) + w4.w * bf2f(s3[j]);
            a[j] = f2bf(v);
        }
        acc0 = __builtin_amdgcn_mfma_f32_16x16x32_bf16(a, bf0, acc0, 0, 0, 0);
        acc1 = __builtin_amdgcn_mfma_f32_16x16x32_bf16(a, bf1, acc1, 0, 0, 0);
        acc2 = __builtin_amdgcn_mfma_f32_16x16x32_bf16(a, bf2, acc2, 0, 0, 0);
        acc3 = __builtin_amdgcn_mfma_f32_16x16x32_bf16(a, bf3, acc3, 0, 0, 0);
    }
    __syncthreads();                     // pos arrays dead; reuse as trans

    // D layout: col=lane&15 (o within tile), row=(lane>>4)*4+reg (pixel within wave)
    int ocol = lane & 15;
    int pr   = wave * 16 + khalf * 4;
    #pragma unroll
    for (int r = 0; r < 4; ++r) {
        trans[(0 * 16 + ocol) * 65 + pr + r] = acc0[r];
        trans[(1 * 16 + ocol) * 65 + pr + r] = acc1[r];
        trans[(2 * 16 + ocol) * 65 + pr + r] = acc2[r];
        trans[(3 * 16 + ocol) * 65 + pr + r] = acc3[r];
    }
    __syncthreads();

    float* ob = out + ((size_t)b * COUT * HH + ho) * WW + wo0;
    for (int i = tid; i < 64 * 64; i += 256) {
        int o = i >> 6, w = i & 63;
        ob[(size_t)o * HW + w] = trans[o * 65 + w];
    }
}

extern "C" void kernel_launch(void* const* d_in, const int* in_sizes, int n_in,
                              void* d_out, int out_size, void* d_ws, size_t ws_size,
                              hipStream_t stream)
{
    const float* x    = (const float*)d_in[0];
    const float* woff = (const float*)d_in[1];
    const float* wdef = (const float*)d_in[2];
    float* out  = (float*)d_out;

    unsigned short* wfrag = (unsigned short*)d_ws;          // 36864 ush = 73.7 KB
    unsigned short* wfo   = wfrag + 36864;                  // 18432 ush = 36.9 KB
    unsigned short* xT    = wfo + 18432;                    // 8*16384*64 ush = 16.8 MB

    hipLaunchKernelGGL(to_chlast_k, dim3(BATCH * HH), dim3(256), 0, stream,
                       x, xT);
    hipLaunchKernelGGL(build_wfrag_k, dim3(COUT * 576 / 256), dim3(256), 0, stream,
                       wdef, wfrag);
    hipLaunchKernelGGL(build_wfo_k, dim3(32 * 576 / 256), dim3(256), 0, stream,
                       woff, wfo);
    hipLaunchKernelGGL(deform_fused_k, dim3(BATCH * HH * 2), dim3(256), 0, stream,
                       xT, (const short8*)wfo, (const short8*)wfrag, out);
}

// Round 8
// 111.302 us; speedup vs baseline: 1.3945x; 1.1044x over previous
//
#include <hip/hip_runtime.h>
#include <hip/hip_bf16.h>

#define BATCH 8
#define CIN   64
#define COUT  64
#define HH    128
#define WW    128
#define HW    (HH * WW)
#define OFFC  18
#define KK    9

typedef __attribute__((ext_vector_type(8))) short short8;
typedef __attribute__((ext_vector_type(8))) unsigned short ushort8;
typedef __attribute__((ext_vector_type(4))) float f32x4;

__device__ __forceinline__ float bf2f(unsigned short u) {
    return __builtin_bit_cast(float, ((unsigned int)u) << 16);
}
__device__ __forceinline__ short f2bf(float v) {
    __hip_bfloat16 h = __float2bfloat16(v);
    return __builtin_bit_cast(short, h);
}

// ------- Kernel X: x (b,c,h,w) f32 -> xT (b,h,w,c) bf16, one (b,ho) row per block -------
__global__ __launch_bounds__(256) void to_chlast_k(
    const float* __restrict__ x, unsigned short* __restrict__ xT)
{
    __shared__ unsigned short t[128 * 72];   // [w][c], pad 72 keeps 16B-aligned ushort8 rows
    int blk = blockIdx.x;                    // b*HH + ho
    int ho = blk & (HH - 1);
    int b  = blk >> 7;
    int tid = threadIdx.x;

    const float* xr = x + (size_t)b * CIN * HW + ho * WW;
    for (int i = tid; i < 2048; i += 256) {  // c = i>>5, 4 consecutive w
        int c = i >> 5, w4 = (i & 31) * 4;
        float4 v = *(const float4*)(xr + (size_t)c * HW + w4);
        t[(w4 + 0) * 72 + c] = (unsigned short)f2bf(v.x);
        t[(w4 + 1) * 72 + c] = (unsigned short)f2bf(v.y);
        t[(w4 + 2) * 72 + c] = (unsigned short)f2bf(v.z);
        t[(w4 + 3) * 72 + c] = (unsigned short)f2bf(v.w);
    }
    __syncthreads();

    unsigned short* orow = xT + (size_t)blk * WW * 64;
    for (int j = tid; j < 1024; j += 256) {  // w = j>>3, 8 channels
        int w = j >> 3, c8 = (j & 7) * 8;
        *(ushort8*)(orow + w * 64 + c8) = *(const ushort8*)(t + w * 72 + c8);
    }
}

// ------- Kernel B: w_deform (o,c,kh,kw) -> bf16 B-fragments wf[kk][nt(4)][lane][8] -------
// B[k=kk*32+(lane>>4)*8+j][col=lane&15] = w[o=nt*16+col][ck=k], ck = tap*64+c
__global__ __launch_bounds__(256) void build_wfrag_k(
    const float* __restrict__ wd, unsigned short* __restrict__ wf)
{
    int idx = blockIdx.x * 256 + threadIdx.x;   // o*576 + ck, 36864 total
    int ck = idx % 576;
    int o  = idx / 576;
    int c = ck & 63, k = ck >> 6;
    float v = wd[o * 576 + c * 9 + k];
    int kk = ck >> 5, nt = o >> 4;
    int lane = (o & 15) | (((ck >> 3) & 3) << 4);
    int j = ck & 7;
    wf[((kk * 4 + nt) * 64 + lane) * 8 + j] = (unsigned short)f2bf(v);
}

// ------- Kernel B2: w_offset (18,64,3,3) -> bf16 B-fragments wfo[kk][nt(2)][lane][8] -------
// N padded 18->32 with zero columns; K = tap*64 + c.
__global__ __launch_bounds__(256) void build_wfo_k(
    const float* __restrict__ wo, unsigned short* __restrict__ wfo)
{
    int idx = blockIdx.x * 256 + threadIdx.x;   // ov*576 + ck, ov = 0..31 (virtual oc)
    if (idx >= 32 * 576) return;
    int ck = idx % 576;
    int ov = idx / 576;
    int c = ck & 63, tap = ck >> 6;
    float v = (ov < OFFC) ? wo[ov * 576 + c * 9 + tap] : 0.f;
    int kk = ck >> 5, nt = ov >> 4;
    int lane = (ov & 15) | (((ck >> 3) & 3) << 4);
    int j = ck & 7;
    wfo[((kk * 2 + nt) * 64 + lane) * 8 + j] = (unsigned short)f2bf(v);
}

// ---------------- Kernel C: fused offsets-conv + gather + deform MFMA ----------------
// Block = ONE FULL ROW (128 pixels) x 64 outputs; 4 waves x 32 pixels (2 A-tiles/wave).
// Two A-tiles share each B-fragment load: halves wf L2 traffic, doubles in-flight
// gathers per wave (8 independent 16B loads per K-step) for latency hiding.
// D-layout gives each lane 4 CONSECUTIVE pixels per o -> direct f32x4 global store
// (no LDS transpose, no 3rd barrier). LDS 37,888 B -> 4 blocks/CU exactly (grid = 4/CU).
// __launch_bounds__(256,4): VGPR cap 128 (R6 showed capping at 32 kills ILP).
__global__ __launch_bounds__(256, 4) void deform_fused_k(
    const unsigned short* __restrict__ xT,
    const short8* __restrict__ wfo,
    const short8* __restrict__ wf, float* __restrict__ out)
{
    __shared__ alignas(16) char smem[37888];
    float*  offsL = (float*)smem;                      // [128][20] = 10240 B
    int2*   posI  = (int2*)(smem + 10240);             // 1152*8  = 9216 B
    float4* posW  = (float4*)(smem + 10240 + 9216);    // 1152*16 = 18432 B

    int tid  = threadIdx.x;
    int blk  = blockIdx.x;               // ho*8 + b  (blk&7 -> XCD owns one batch)
    int b    = blk & 7;
    int ho   = blk >> 3;

    const unsigned short* pT = xT + (size_t)b * HW * 64;

    int lane  = tid & 63;
    int wave  = tid >> 6;
    int prow  = lane & 15;               // pixel row within A-tile
    int khalf = lane >> 4;               // k-subchunk
    int px0   = wave * 32 + prow;        // tile-0 pixel (= wo)
    int px1   = px0 + 16;                // tile-1 pixel

    // ---- phase A: offsets = conv3x3(x, w_offset) via MFMA (2 pixel-tiles) ----
    {
        f32x4 oa00 = {0.f,0.f,0.f,0.f}, oa01 = {0.f,0.f,0.f,0.f};
        f32x4 oa10 = {0.f,0.f,0.f,0.f}, oa11 = {0.f,0.f,0.f,0.f};
        #pragma unroll
        for (int kk = 0; kk < 18; ++kk) {
            int tap = kk >> 1;
            int y   = ho + tap / 3 - 1;
            int dx  = tap % 3 - 1;
            int c0  = ((kk & 1) << 5) + (khalf << 3);
            short8 a0 = {0,0,0,0,0,0,0,0};
            short8 a1 = {0,0,0,0,0,0,0,0};
            int xw0 = px0 + dx, xw1 = px1 + dx;
            if ((unsigned)y < HH && (unsigned)xw0 < WW)
                a0 = *(const short8*)(pT + (((size_t)(y * WW + xw0)) << 6) + c0);
            if ((unsigned)y < HH && (unsigned)xw1 < WW)
                a1 = *(const short8*)(pT + (((size_t)(y * WW + xw1)) << 6) + c0);
            short8 b0 = wfo[(kk * 2 + 0) * 64 + lane];
            short8 b1 = wfo[(kk * 2 + 1) * 64 + lane];
            oa00 = __builtin_amdgcn_mfma_f32_16x16x32_bf16(a0, b0, oa00, 0, 0, 0);
            oa01 = __builtin_amdgcn_mfma_f32_16x16x32_bf16(a0, b1, oa01, 0, 0, 0);
            oa10 = __builtin_amdgcn_mfma_f32_16x16x32_bf16(a1, b0, oa10, 0, 0, 0);
            oa11 = __builtin_amdgcn_mfma_f32_16x16x32_bf16(a1, b1, oa11, 0, 0, 0);
        }
        int ocol = lane & 15;
        int pix0 = wave * 32 + khalf * 4;
        #pragma unroll
        for (int r = 0; r < 4; ++r) {
            offsL[(pix0 + r) * 20 + ocol]      = oa00[r];
            offsL[(pix0 + 16 + r) * 20 + ocol] = oa10[r];
        }
        if (ocol < 2) {
            #pragma unroll
            for (int r = 0; r < 4; ++r) {
                offsL[(pix0 + r) * 20 + 16 + ocol]      = oa01[r];
                offsL[(pix0 + 16 + r) * 20 + 16 + ocol] = oa11[r];
            }
        }
    }
    __syncthreads();

    // ---- phase 0: 128 pixels x 9 taps -> compressed corner indices + pre-masked weights ----
    for (int e = tid; e < 1152; e += 256) {
        int p = e / 9, k = e - p * 9;
        float dy = offsL[p * 20 + 2 * k];
        float dx = offsL[p * 20 + 2 * k + 1];
        float yy = (float)(ho - 1 + k / 3) + dy;
        float xx = (float)(p - 1 + k % 3) + dx;
        float y0 = floorf(yy), x0 = floorf(xx);
        float wy1 = yy - y0, wx1 = xx - x0;
        float wy0 = 1.f - wy1, wx0 = 1.f - wx1;
        bool valid = (yy > -1.f) && (yy < (float)HH) && (xx > -1.f) && (xx < (float)WW);
        int y0i = (int)y0, x0i = (int)x0;
        bool iy0 = (unsigned)y0i < HH, iy1 = (unsigned)(y0i + 1) < HH;
        bool ix0 = (unsigned)x0i < WW, ix1 = (unsigned)(x0i + 1) < WW;
        float m00 = (valid && iy0 && ix0) ? 1.f : 0.f;
        float m01 = (valid && iy0 && ix1) ? 1.f : 0.f;
        float m10 = (valid && iy1 && ix0) ? 1.f : 0.f;
        float m11 = (valid && iy1 && ix1) ? 1.f : 0.f;
        int yc0 = min(max(y0i, 0), HH - 1), yc1 = min(max(y0i + 1, 0), HH - 1);
        int xc0 = min(max(x0i, 0), WW - 1), xc1 = min(max(x0i + 1, 0), WW - 1);
        int idx00 = yc0 * WW + xc0;
        int ddx   = xc1 - xc0;                   // 0 or 1
        int dyw   = (yc1 - yc0) * WW;            // 0 or WW
        posI[e] = make_int2(idx00, (dyw << 1) | ddx);
        posW[e] = make_float4(wy0 * wx0 * m00, wy0 * wx1 * m01, wy1 * wx0 * m10, wy1 * wx1 * m11);
    }
    __syncthreads();

    // ---- phase 1: gather + MFMA, 2 A-tiles sharing B-fragments ----
    int eb0 = px0 * 9, eb1 = px1 * 9;

    f32x4 accA0 = {0.f,0.f,0.f,0.f}, accA1 = {0.f,0.f,0.f,0.f};
    f32x4 accA2 = {0.f,0.f,0.f,0.f}, accA3 = {0.f,0.f,0.f,0.f};
    f32x4 accB0 = {0.f,0.f,0.f,0.f}, accB1 = {0.f,0.f,0.f,0.f};
    f32x4 accB2 = {0.f,0.f,0.f,0.f}, accB3 = {0.f,0.f,0.f,0.f};

    #pragma unroll 2
    for (int kk = 0; kk < 18; ++kk) {
        int tap = kk >> 1;
        short8 bf0 = wf[(kk * 4 + 0) * 64 + lane];
        short8 bf1 = wf[(kk * 4 + 1) * 64 + lane];
        short8 bf2 = wf[(kk * 4 + 2) * 64 + lane];
        short8 bf3 = wf[(kk * 4 + 3) * 64 + lane];
        int2   ioA = posI[eb0 + tap];
        float4 wA  = posW[eb0 + tap];
        int2   ioB = posI[eb1 + tap];
        float4 wB  = posW[eb1 + tap];
        int c0 = ((kk & 1) << 5) + (khalf << 3);
        const unsigned short* bp = pT + c0;

        int iA00 = ioA.x, dA = ioA.y & 1, yA = ioA.y >> 1;
        int iB00 = ioB.x, dB = ioB.y & 1, yB = ioB.y >> 1;
        ushort8 sA0 = *(const ushort8*)(bp + (size_t)iA00 * 64);
        ushort8 sA1 = *(const ushort8*)(bp + (size_t)(iA00 + dA) * 64);
        ushort8 sA2 = *(const ushort8*)(bp + (size_t)(iA00 + yA) * 64);
        ushort8 sA3 = *(const ushort8*)(bp + (size_t)(iA00 + yA + dA) * 64);
        ushort8 sB0 = *(const ushort8*)(bp + (size_t)iB00 * 64);
        ushort8 sB1 = *(const ushort8*)(bp + (size_t)(iB00 + dB) * 64);
        ushort8 sB2 = *(const ushort8*)(bp + (size_t)(iB00 + yB) * 64);
        ushort8 sB3 = *(const ushort8*)(bp + (size_t)(iB00 + yB + dB) * 64);

        short8 aA, aB;
        #pragma unroll
        for (int j = 0; j < 8; ++j) {
            float vA = wA.x * bf2f(sA0[j]) + wA.y * bf2f(sA1[j])
                     + wA.z * bf2f(sA2[j]) + wA.w * bf2f(sA3[j]);
            float vB = wB.x * bf2f(sB0[j]) + wB.y * bf2f(sB1[j])
                     + wB.z * bf2f(sB2[j]) + wB.w * bf2f(sB3[j]);
            aA[j] = f2bf(vA);
            aB[j] = f2bf(vB);
        }
        accA0 = __builtin_amdgcn_mfma_f32_16x16x32_bf16(aA, bf0, accA0, 0, 0, 0);
        accA1 = __builtin_amdgcn_mfma_f32_16x16x32_bf16(aA, bf1, accA1, 0, 0, 0);
        accA2 = __builtin_amdgcn_mfma_f32_16x16x32_bf16(aA, bf2, accA2, 0, 0, 0);
        accA3 = __builtin_amdgcn_mfma_f32_16x16x32_bf16(aA, bf3, accA3, 0, 0, 0);
        accB0 = __builtin_amdgcn_mfma_f32_16x16x32_bf16(aB, bf0, accB0, 0, 0, 0);
        accB1 = __builtin_amdgcn_mfma_f32_16x16x32_bf16(aB, bf1, accB1, 0, 0, 0);
        accB2 = __builtin_amdgcn_mfma_f32_16x16x32_bf16(aB, bf2, accB2, 0, 0, 0);
        accB3 = __builtin_amdgcn_mfma_f32_16x16x32_bf16(aB, bf3, accB3, 0, 0, 0);
    }

    // ---- epilogue: direct f32x4 stores (lane holds 4 consecutive pixels per o) ----
    {
        int ocol = lane & 15;
        int pixA = wave * 32 + khalf * 4;        // tile-0 pixel base
        float* ob = out + ((size_t)b * COUT) * HW + ho * WW;
        f32x4* dst;
        dst = (f32x4*)(ob + (size_t)(0 * 16 + ocol) * HW + pixA);
        dst[0] = accA0;  dst[4] = accB0;         // +16 pixels = 4 f32x4
        dst = (f32x4*)(ob + (size_t)(1 * 16 + ocol) * HW + pixA);
        dst[0] = accA1;  dst[4] = accB1;
        dst = (f32x4*)(ob + (size_t)(2 * 16 + ocol) * HW + pixA);
        dst[0] = accA2;  dst[4] = accB2;
        dst = (f32x4*)(ob + (size_t)(3 * 16 + ocol) * HW + pixA);
        dst[0] = accA3;  dst[4] = accB3;
    }
}

extern "C" void kernel_launch(void* const* d_in, const int* in_sizes, int n_in,
                              void* d_out, int out_size, void* d_ws, size_t ws_size,
                              hipStream_t stream)
{
    const float* x    = (const float*)d_in[0];
    const float* woff = (const float*)d_in[1];
    const float* wdef = (const float*)d_in[2];
    float* out  = (float*)d_out;

    unsigned short* wfrag = (unsigned short*)d_ws;          // 36864 ush = 73.7 KB
    unsigned short* wfo   = wfrag + 36864;                  // 18432 ush = 36.9 KB
    unsigned short* xT    = wfo + 18432;                    // 8*16384*64 ush = 16.8 MB

    hipLaunchKernelGGL(to_chlast_k, dim3(BATCH * HH), dim3(256), 0, stream,
                       x, xT);
    hipLaunchKernelGGL(build_wfrag_k, dim3(COUT * 576 / 256), dim3(256), 0, stream,
                       wdef, wfrag);
    hipLaunchKernelGGL(build_wfo_k, dim3(32 * 576 / 256), dim3(256), 0, stream,
                       woff, wfo);
    hipLaunchKernelGGL(deform_fused_k, dim3(HH * 8), dim3(256), 0, stream,
                       xT, (const short8*)wfo, (const short8*)wfrag, out);
}